// Round 3
// baseline (497.704 us; speedup 1.0000x reference)
//
#include <hip/hip_runtime.h>
#include <math.h>

#define BB 32
#define HH 16
#define DD 128
#define BSZ 16
#define MAXBLK 64
#define NCHUNK 4      // chunks per (b,h); 4 * 256 = 1024 = max context
#define CT 256        // tokens per chunk
#define CBLK 16       // paged blocks per chunk
#define SCALE 0.08838834764831845f

// Flash-decode chunk kernel: one workgroup (4 waves) per (b, h, chunk).
// float4 (dwordx4) global loads throughout. The new token (position len-1)
// is folded in from new_k/new_v inline — the paged caches are never mutated.
__global__ __launch_bounds__(256) void attn_chunk_kernel(
    const float* __restrict__ q, const float* __restrict__ newk,
    const float* __restrict__ newv, const float* __restrict__ kc,
    const float* __restrict__ vc, const int* __restrict__ block_tables,
    const int* __restrict__ context_lens,
    float* __restrict__ o_part, float* __restrict__ m_part,
    float* __restrict__ l_part)
{
    __shared__ float s_scores[CT];
    __shared__ float s_q[DD];
    __shared__ float s_red[8];
    __shared__ float s_out[4][DD];

    int gid  = blockIdx.x;         // bh * NCHUNK + c
    int c    = gid & (NCHUNK - 1);
    int bh   = gid >> 2;
    int b    = bh >> 4;
    int h    = bh & 15;
    int tid  = threadIdx.x;
    int wave = tid >> 6;
    int lane = tid & 63;
    int hi   = lane >> 5;          // which 32-lane half
    int dq   = (lane & 31) * 4;    // V-phase output-dim base

    int len    = context_lens[b];
    int cstart = c * CT;
    if (cstart >= len) return;     // chunk entirely beyond context

    int nblk   = (len + 15) >> 4;
    int cb0    = c * CBLK;
    int cb_end = min(nblk, cb0 + CBLK);
    int last   = len - 1;
    bool haslast = (last >> 8) == c;   // this chunk holds the new token

    if (tid < DD) s_q[tid] = q[(size_t)bh * DD + tid] * SCALE;
    __syncthreads();

    // K phase q fragments: instruction p covers d_hi = 2p + hi; this lane's
    // x-offset within the token's 8-float x-row is 4*(lane&1).
    int xo = (lane & 1) * 4;
    float4 rq[8];
#pragma unroll
    for (int p = 0; p < 8; ++p)
        rq[p] = *(const float4*)&s_q[(2 * p + hi) * 8 + xo];

    const int* bt = block_tables + b * MAXBLK;

    // ---- Phase 1: scores. K block layout per (pb,h): [d_hi=16][tok=16][x=8]
    // = 2048 floats. Each dwordx4 step covers 256 floats = 2 d_hi slices.
    for (int cb = cb0 + wave; cb < cb_end; cb += 4) {
        int pb = bt[cb];
        const float* kbase = kc + ((size_t)pb * HH + h) * 2048 + lane * 4;
        float acc = 0.f;
#pragma unroll
        for (int p = 0; p < 8; ++p) {
            float4 kv = *(const float4*)(kbase + p * 256);
            acc += rq[p].x * kv.x + rq[p].y * kv.y
                 + rq[p].z * kv.z + rq[p].w * kv.w;
        }
        // token t partial lives in lanes {2t, 2t+1, 2t+32, 2t+33}
        acc += __shfl_xor(acc, 1);
        acc += __shfl_xor(acc, 32);
        if (hi == 0 && (lane & 1) == 0) {
            int t = lane >> 1;
            int pidx = cb * 16 + t;
            s_scores[(cb - cb0) * 16 + t] = (pidx < len) ? acc : -INFINITY;
        }
    }
    __syncthreads();

    // ---- New-token score fix: recompute score at `last` from new_k.
    if (haslast && wave == 0) {
        float2 nk = *(const float2*)&newk[(size_t)bh * DD + 2 * lane];
        float part = s_q[2 * lane] * nk.x + s_q[2 * lane + 1] * nk.y;
#pragma unroll
        for (int off = 32; off; off >>= 1) part += __shfl_xor(part, off);
        if (lane == 0) s_scores[last - cstart] = part;
    }
    __syncthreads();

    // ---- Phase 2: local softmax over padded = (cb_end-cb0)*16 entries.
    int padded = (cb_end - cb0) * 16;
    float mloc = (tid < padded) ? s_scores[tid] : -INFINITY;
#pragma unroll
    for (int off = 32; off; off >>= 1) mloc = fmaxf(mloc, __shfl_xor(mloc, off));
    if (lane == 0) s_red[wave] = mloc;
    __syncthreads();
    float m = fmaxf(fmaxf(s_red[0], s_red[1]), fmaxf(s_red[2], s_red[3]));

    float e = 0.f;
    if (tid < padded) {
        e = __expf(s_scores[tid] - m);
        s_scores[tid] = e;              // unnormalized weights
    }
    float ssum = e;
#pragma unroll
    for (int off = 32; off; off >>= 1) ssum += __shfl_xor(ssum, off);
    if (lane == 0) s_red[4 + wave] = ssum;
    __syncthreads();
    float lsum = s_red[4] + s_red[5] + s_red[6] + s_red[7];

    // ---- Phase 3: o_c = sum_p e[p] * V[p,:]. V block = [tok=16][d=128].
    // Each dwordx4 step covers 256 floats = 2 tokens; lane covers dims dq..dq+3
    // of token t = 2*it + hi.
    float4 nv4 = make_float4(0.f, 0.f, 0.f, 0.f);
    if (haslast) nv4 = *(const float4*)&newv[(size_t)bh * DD + dq];
    int lastLocal = haslast ? last : -1;

    float4 acc4 = make_float4(0.f, 0.f, 0.f, 0.f);
    for (int cb = cb0 + wave; cb < cb_end; cb += 4) {
        int pb = bt[cb];
        const float* vbase = vc + ((size_t)pb * HH + h) * 2048 + lane * 4;
#pragma unroll
        for (int it = 0; it < 8; ++it) {
            int t = 2 * it + hi;
            float w = s_scores[(cb - cb0) * 16 + t];   // 0 for masked tokens
            float4 vv = *(const float4*)(vbase + it * 256);
            if (cb * 16 + t == lastLocal) vv = nv4;
            acc4.x += w * vv.x;
            acc4.y += w * vv.y;
            acc4.z += w * vv.z;
            acc4.w += w * vv.w;
        }
    }
    // combine the two token-parity halves: lanes l and l^32 hold same dims
    acc4.x += __shfl_xor(acc4.x, 32);
    acc4.y += __shfl_xor(acc4.y, 32);
    acc4.z += __shfl_xor(acc4.z, 32);
    acc4.w += __shfl_xor(acc4.w, 32);
    if (hi == 0)
        *(float4*)&s_out[wave][dq] = acc4;
    __syncthreads();

    if (tid < 32) {
        float4 a = *(const float4*)&s_out[0][4 * tid];
        float4 bb2 = *(const float4*)&s_out[1][4 * tid];
        float4 cc = *(const float4*)&s_out[2][4 * tid];
        float4 dd = *(const float4*)&s_out[3][4 * tid];
        float4 o;
        o.x = a.x + bb2.x + cc.x + dd.x;
        o.y = a.y + bb2.y + cc.y + dd.y;
        o.z = a.z + bb2.z + cc.z + dd.z;
        o.w = a.w + bb2.w + cc.w + dd.w;
        *(float4*)&o_part[(size_t)gid * DD + 4 * tid] = o;
    }
    if (tid == 0) {
        m_part[gid] = m;
        l_part[gid] = lsum;
    }
}

// Log-sum-exp merge of the per-chunk partials. One block (2 waves) per (b,h).
__global__ __launch_bounds__(128) void attn_combine_kernel(
    const float* __restrict__ o_part, const float* __restrict__ m_part,
    const float* __restrict__ l_part, const int* __restrict__ context_lens,
    float* __restrict__ out)
{
    int bh  = blockIdx.x;
    int b   = bh >> 4;
    int tid = threadIdx.x;
    int len = context_lens[b];
    int nc  = (len + CT - 1) >> 8;

    float mi[NCHUNK];
    float m_g = -INFINITY;
    for (int i = 0; i < nc; ++i) {
        mi[i] = m_part[bh * NCHUNK + i];
        m_g = fmaxf(m_g, mi[i]);
    }
    float acc = 0.f, lg = 0.f;
    for (int i = 0; i < nc; ++i) {
        float w = __expf(mi[i] - m_g);
        lg  += w * l_part[bh * NCHUNK + i];
        acc += w * o_part[(size_t)(bh * NCHUNK + i) * DD + tid];
    }
    out[(size_t)bh * DD + tid] = acc / lg;
}

extern "C" void kernel_launch(void* const* d_in, const int* in_sizes, int n_in,
                              void* d_out, int out_size, void* d_ws, size_t ws_size,
                              hipStream_t stream) {
    const float* query        = (const float*)d_in[0];
    const float* key          = (const float*)d_in[1];
    const float* value        = (const float*)d_in[2];
    const float* key_cache    = (const float*)d_in[3];
    const float* value_cache  = (const float*)d_in[4];
    const int*   block_tables = (const int*)d_in[5];
    const int*   context_lens = (const int*)d_in[6];
    float*       out          = (float*)d_out;

    // Workspace layout: o_part [B*H*NCHUNK, 128] | m_part | l_part
    float* o_part = (float*)d_ws;
    float* m_part = o_part + (size_t)BB * HH * NCHUNK * DD;
    float* l_part = m_part + (size_t)BB * HH * NCHUNK;

    attn_chunk_kernel<<<BB * HH * NCHUNK, 256, 0, stream>>>(
        query, key, value, key_cache, value_cache, block_tables,
        context_lens, o_part, m_part, l_part);
    attn_combine_kernel<<<BB * HH, 128, 0, stream>>>(
        o_part, m_part, l_part, context_lens, out);
}